// Round 1
// baseline (264.647 us; speedup 1.0000x reference)
//
#include <hip/hip_runtime.h>
#include <hip/hip_bf16.h>
#include <math.h>

#define NBATCH 32
#define IMGSZ  224
#define NR     400
#define NA     1024
#define ED     96
#define SROW   266   // s_samp row stride in elems (256 cols + 10; odd dword)

typedef __attribute__((ext_vector_type(8))) __bf16 bf16x8;
typedef __attribute__((ext_vector_type(8), aligned(8))) __bf16 bf16x8u;
typedef __attribute__((ext_vector_type(4), aligned(8))) __bf16 bf16x4a;
typedef __attribute__((ext_vector_type(4))) __bf16 bf16x4;
typedef __attribute__((ext_vector_type(4))) float f32x4;

union frag_u { struct { bf16x4a lo, hi; } p; bf16x8 v; };

// ---------------------------------------------------------------------------
// ws layout:
//   rtab    f32 [32][400]
//   costab  f32 [1024]  (pre-scaled by 223/224)
//   sintab  f32 [1024]  (pre-scaled by 223/224)
//   w2f     bf16 [20*3*6][64][8]  fragment-major w2, j ^ ((ka+icb)&1)*4
//   w1f     bf16 [12][64][8]      fragment-major w1 (grp = ks*6+ot), k>=60 -> 0
//   xp      bf16 [32][224][224][4] channels-last packed image
// ---------------------------------------------------------------------------

#define PACK_N   (NBATCH*IMGSZ*IMGSZ)
#define PACK_N4  (PACK_N/4)               // 401408, exact
#define PACK_B   ((PACK_N4 + 255)/256)    // 1568, exact
#define PREP_N   (ED*ED*20 + 12*64*8 + NBATCH*NR + NA + NBATCH)
#define PREP_B   ((PREP_N + 255)/256)

// merged image pack (4 px/thread, float4 loads) + tables + weight reorder
__global__ __launch_bounds__(256)
void prep_pack_kernel(const float* __restrict__ x,
                      const float* __restrict__ dist,
                      const float* __restrict__ w1,
                      const float* __restrict__ w2,
                      __bf16* __restrict__ xp,
                      float* __restrict__ rtab,
                      float* __restrict__ costab,
                      float* __restrict__ sintab,
                      __bf16* __restrict__ w2f,
                      __bf16* __restrict__ w1f,
                      float* __restrict__ theta_out) {
    const float PI = 3.14159265358979323846f;
    const float SC = 223.0f / 224.0f;
    int bid = blockIdx.x;

    if (bid < PACK_B) {                       // ---- image pack, 4 px/thread
        int i4 = bid*256 + threadIdx.x;
        if (i4 >= PACK_N4) return;
        int idx = i4 * 4;                     // pixel base; 50176 % 4 == 0 so
        int b  = idx / (IMGSZ*IMGSZ);         // all 4 px share one batch
        int px = idx - b*(IMGSZ*IMGSZ);
        const float* p = x + (size_t)b*3*IMGSZ*IMGSZ + px;
        f32x4 cr = *(const f32x4*)(p);
        f32x4 cg = *(const f32x4*)(p + IMGSZ*IMGSZ);
        f32x4 cb = *(const f32x4*)(p + 2*IMGSZ*IMGSZ);
        bf16x8 o0, o1;
        o0[0] = (__bf16)cr[0]; o0[1] = (__bf16)cg[0]; o0[2] = (__bf16)cb[0]; o0[3] = (__bf16)0.0f;
        o0[4] = (__bf16)cr[1]; o0[5] = (__bf16)cg[1]; o0[6] = (__bf16)cb[1]; o0[7] = (__bf16)0.0f;
        o1[0] = (__bf16)cr[2]; o1[1] = (__bf16)cg[2]; o1[2] = (__bf16)cb[2]; o1[3] = (__bf16)0.0f;
        o1[4] = (__bf16)cr[3]; o1[5] = (__bf16)cg[3]; o1[6] = (__bf16)cb[3]; o1[7] = (__bf16)0.0f;
        *(bf16x8*)(xp + (size_t)idx*4)     = o0;   // 16B, 32B-aligned
        *(bf16x8*)(xp + (size_t)idx*4 + 8) = o1;
        return;
    }

    int idx = (bid - PACK_B)*256 + threadIdx.x;
    if (idx < ED*ED*20) {
        // w2f: [(p*3+icb)*6+nt][lane][j], ic = icb*32+(lane>>4)*8+(j^sw)
        int j    = idx & 7;
        int lane = (idx >> 3) & 63;
        int grp  = idx >> 9;
        int nt   = grp % 6;
        int t    = grp / 6;
        int icb  = t % 3;
        int p    = t / 3;
        int sw   = (((p & 3) + icb) & 1) * 4;
        int oc = nt*16 + (lane & 15);
        int ic = icb*32 + (lane >> 4)*8 + (j ^ sw);
        w2f[idx] = (__bf16)w2[((size_t)(oc*ED + ic)*5 + (p >> 2))*4 + (p & 3)];
    } else if (idx < ED*ED*20 + 12*64*8) {
        // w1f: [grp=ks*6+ot][lane][j], A-frag value w1[oc][k]
        int i2   = idx - ED*ED*20;
        int j    = i2 & 7;
        int lane = (i2 >> 3) & 63;
        int grp  = i2 >> 9;
        int ks = grp / 6, ot = grp % 6;
        int oc = ot*16 + (lane & 15);
        int k  = ks*32 + (lane >> 4)*8 + j;
        w1f[i2] = (k < 60) ? (__bf16)w1[oc*60 + k] : (__bf16)0.0f;
    } else if (idx < ED*ED*20 + 12*64*8 + NBATCH*NR) {
        int i2 = idx - ED*ED*20 - 12*64*8;
        int b = i2 / NR, i = i2 % NR;
        float c0 = 0.2f + dist[b*4+0];
        float c1 = 0.2f + dist[b*4+1];
        float c2 = 0.2f + dist[b*4+2];
        float c3 = 0.2f + dist[b*4+3];
        float tmax = 0.5f * PI;
        float t  = tmax * ((float)i + 0.5f) / (float)NR;
        float t2 = t * t;
        float pt = t * (c0 + t2*(c1 + t2*(c2 + t2*c3)));
        float tm2 = tmax * tmax;
        float pm = tmax * (c0 + tm2*(c1 + tm2*(c2 + tm2*c3)));
        rtab[i2] = pt / pm * (0.5f * (float)IMGSZ);
    } else if (idx < ED*ED*20 + 12*64*8 + NBATCH*NR + NA) {
        int j = idx - ED*ED*20 - 12*64*8 - NBATCH*NR;
        float phi = 2.0f * PI * ((float)j + 0.5f) / (float)NA;
        costab[j] = cosf(phi) * SC;
        sintab[j] = sinf(phi) * SC;
    } else if (idx < PREP_N) {
        theta_out[idx - (ED*ED*20 + 12*64*8 + NBATCH*NR + NA)] = 0.5f * PI;
    }
}

// ---------------------------------------------------------------------------
// Mega kernel: polar bilinear sample (block-private region) -> conv1 (MFMA,
// D[oc][pixel]) -> t1f (conflict-free layout) -> conv2 (MFMA, wave =
// ka-quarter, register-accumulated over kr) -> reduce -> out.
// Block = (b, aq az-quarter, r2). Grid 2048, 256 thr = 4 waves.
// LDS 20288 B (w1 frags now read from global: identical 6KB for every block,
// L1/L2-resident broadcast) -> 8 blocks/CU resident = 32 waves = 100%
// occupancy, and grid 2048 = exactly 8 blocks/CU -> single residency round.
// Loop body order: conv1 | bar | conv2 | sched_barrier | sample(kr+1) —
// so conv2's vmcnt waits never drain the sample gathers (in-order FIFO;
// conv1's w1 global loads complete before conv2's w2f loads issue).
// ---------------------------------------------------------------------------
__global__ __launch_bounds__(256, 8)
void mega_kernel(const __bf16* __restrict__ xp,
                 const __bf16* __restrict__ w1f_g,
                 const __bf16* __restrict__ w2f,
                 const float* __restrict__ b1,
                 const float* __restrict__ b2,
                 const float* __restrict__ rtab,
                 const float* __restrict__ costab,
                 const float* __restrict__ sintab,
                 float* __restrict__ out) {
    __shared__ __attribute__((aligned(16))) char smem[20288];
    __bf16* s_samp = (__bf16*)smem;             // [15][266] elems 0..3989
    __bf16* t1f    = (__bf16*)(smem + 8000);    // [12 kk][4 quad][16 m][8]
    float*  red    = (float*)smem;              // [3][16][98] fp32 (aliases)

    int tid = threadIdx.x;
    int bid = blockIdx.x;                       // 2048
    int r2 = bid & 15;
    int aq = (bid >> 4) & 3;
    int b  = bid >> 6;
    int wave = tid >> 6, lane = tid & 63, l15 = lane & 15, quad = lane >> 4;

    // per-thread sampling constants: one azimuth column
    int az = aq*256 + tid;
    float sn = sintab[az];
    float cs = costab[az];
    const __bf16* xpb = xp + (size_t)b*IMGSZ*IMGSZ*4;
    const float* rb = rtab + b*NR + r2*25;

    f32x4 acc2[6];
    #pragma unroll
    for (int nt = 0; nt < 6; ++nt) acc2[nt] = (f32x4){0.f,0.f,0.f,0.f};

    // sample 5 radius rows (kr) x 3 ch into s_samp; stride-1 bf16 stores (free)
    auto sample = [&](int kr) {
        #pragma unroll
        for (int q = 0; q < 5; ++q) {
            float r  = rb[kr*5 + q];                       // wave-uniform
            float gx = fmaf(r, sn, 111.5f);
            float gy = fmaf(r, cs, 111.5f);
            float x0f = floorf(gx), y0f = floorf(gy);
            float wx1 = gx - x0f, wx0 = 1.0f - wx1;
            float wy1 = gy - y0f, wy0 = 1.0f - wy1;
            int ix = (int)x0f, iy = (int)y0f;
            ix = min(max(ix, 0), IMGSZ-2);                 // always in-bounds
            iy = min(max(iy, 0), IMGSZ-2);
            const __bf16* img = xpb + ((size_t)iy*IMGSZ + ix)*4;
            bf16x8u p0 = *(const bf16x8u*)img;
            bf16x8u p1 = *(const bf16x8u*)(img + IMGSZ*4);
            float w00 = wy0*wx0, w01 = wy0*wx1, w10 = wy1*wx0, w11 = wy1*wx1;
            #pragma unroll
            for (int c = 0; c < 3; ++c) {
                float v = w00*(float)p0[c] + w01*(float)p0[4+c]
                        + w10*(float)p1[c] + w11*(float)p1[4+c];
                s_samp[(c*5 + q)*SROW + tid] = (__bf16)v;
            }
        }
    };

    sample(0);

    for (int kr = 0; kr < 5; ++kr) {
        __syncthreads();   // A: samples(kr) visible; prev conv2 t1f reads done

        // ---- conv1: wave = pixel-tile, pixel = wave*16 + l15 in [0,64)
        int colb = (wave*16 + l15)*4;
        f32x4 acc1[6];
        #pragma unroll
        for (int ot = 0; ot < 6; ++ot) acc1[ot] = (f32x4){0.f,0.f,0.f,0.f};

        frag_u fa, fb;
        fa.p.lo = *(const bf16x4a*)&s_samp[(quad*2    )*SROW + colb];
        fa.p.hi = *(const bf16x4a*)&s_samp[(quad*2 + 1)*SROW + colb];
        fb.p.lo = *(const bf16x4a*)&s_samp[(8 + quad*2)*SROW + colb];
        if (quad == 3) fb.p.hi = (bf16x4a){};
        else           fb.p.hi = *(const bf16x4a*)&s_samp[(9 + quad*2)*SROW + colb];

        #pragma unroll
        for (int ot = 0; ot < 6; ++ot) {
            // w1 fragments from global: same 6KB for all 2048 blocks -> L1/L2
            bf16x8 wf0 = *(const bf16x8*)(w1f_g + (ot     )*512 + lane*8);
            bf16x8 wf1 = *(const bf16x8*)(w1f_g + (6 + ot )*512 + lane*8);
            acc1[ot] = __builtin_amdgcn_mfma_f32_16x16x32_bf16(wf0, fa.v, acc1[ot], 0, 0, 0);
            acc1[ot] = __builtin_amdgcn_mfma_f32_16x16x32_bf16(wf1, fb.v, acc1[ot], 0, 0, 0);
        }

        // epilogue: col=l15 (pixel), row=quad*4+r (oc=ic); scatter to t1f
        int pixel = wave*16 + l15;
        int a2l = pixel >> 2, ka = pixel & 3;
        #pragma unroll
        for (int ot = 0; ot < 6; ++ot) {
            f32x4 v = acc1[ot] + *(const f32x4*)(b1 + ot*16 + quad*4);
            bf16x4a wv;
            wv[0] = (__bf16)v[0]; wv[1] = (__bf16)v[1];
            wv[2] = (__bf16)v[2]; wv[3] = (__bf16)v[3];
            int icbase = ot*16 + quad*4;
            int kk = ka*3 + (icbase >> 5);
            int qT = (icbase >> 3) & 3;
            int jb = (icbase & 7) ^ ((kk & 1)*4);
            *(bf16x4a*)&t1f[((kk*4 + qT)*16 + a2l)*8 + jb] = wv;
        }
        __syncthreads();   // B: t1f ready; s_samp reads done

        // ---- conv2 FIRST: wave's ka = wave; 3 k-steps (vm loads self-owned)
        #pragma unroll
        for (int icb = 0; icb < 3; ++icb) {
            int kk = wave*3 + icb;
            int p  = kr*4 + wave;
            bf16x8 af = *(const bf16x8*)&t1f[(kk*64 + lane)*8];   // lane-contig
            const __bf16* wp = w2f + (size_t)((p*3 + icb)*6)*512 + lane*8;
            #pragma unroll
            for (int nt = 0; nt < 6; ++nt) {
                bf16x8 bf = *(const bf16x8*)(wp + nt*512);
                acc2[nt] = __builtin_amdgcn_mfma_f32_16x16x32_bf16(af, bf, acc2[nt], 0, 0, 0);
            }
        }

        // keep sample's gathers AFTER conv2's loads (vmcnt FIFO ordering)
        __builtin_amdgcn_sched_barrier(0);

        if (kr < 4) sample(kr + 1);   // gather latency hidden by other waves
    }

    // ---- ka-quarter reduction (red aliases s_samp+t1f: 18816 B < 20288 B)
    __syncthreads();
    if (wave) {
        float* rw = red + (wave - 1)*1568;     // 16*98
        #pragma unroll
        for (int nt = 0; nt < 6; ++nt)
            #pragma unroll
            for (int r = 0; r < 4; ++r)
                rw[(quad*4 + r)*98 + nt*16 + l15] = acc2[nt][r];
    }
    __syncthreads();
    if (wave == 0) {
        size_t ob = ((size_t)b*1024 + r2*64 + aq*16)*ED;
        #pragma unroll
        for (int nt = 0; nt < 6; ++nt) {
            int oc = nt*16 + l15;
            float bias = b2[oc];
            #pragma unroll
            for (int r = 0; r < 4; ++r) {
                int row = quad*4 + r;
                float v = acc2[nt][r] + bias
                        + red[row*98 + oc]
                        + red[1568 + row*98 + oc]
                        + red[3136 + row*98 + oc];
                out[ob + (size_t)row*ED + oc] = v;
            }
        }
    }
}

extern "C" void kernel_launch(void* const* d_in, const int* in_sizes, int n_in,
                              void* d_out, int out_size, void* d_ws, size_t ws_size,
                              hipStream_t stream) {
    const float* x    = (const float*)d_in[0];
    const float* dist = (const float*)d_in[1];
    const float* w1   = (const float*)d_in[2];
    const float* b1   = (const float*)d_in[3];
    const float* w2   = (const float*)d_in[4];
    const float* b2   = (const float*)d_in[5];
    float* out = (float*)d_out;

    float* rtab   = (float*)d_ws;                 // 12800
    float* costab = rtab + NBATCH*NR;             // 1024
    float* sintab = costab + NA;                  // 1024
    __bf16* w2f   = (__bf16*)(sintab + NA);       // 184320 bf16
    __bf16* w1f   = w2f + ED*ED*20;               // 6144 bf16
    __bf16* xp    = w1f + 12*64*8;                // 32*224*224*4 bf16

    float* theta_out = out + (size_t)NBATCH*1024*ED;

    prep_pack_kernel<<<PACK_B + PREP_B, 256, 0, stream>>>(
        x, dist, w1, w2, xp, rtab, costab, sintab, w2f, w1f, theta_out);
    mega_kernel<<<NBATCH*16*4, 256, 0, stream>>>(
        xp, w1f, w2f, b1, b2, rtab, costab, sintab, out);
}

// Round 2
// 165.037 us; speedup vs baseline: 1.6036x; 1.6036x over previous
//
#include <hip/hip_runtime.h>
#include <hip/hip_bf16.h>
#include <math.h>

#define NBATCH 32
#define IMGSZ  224
#define NR     400
#define NA     1024
#define ED     96
#define SROW   266   // s_samp row stride in elems (256 cols + 10; odd dword)

typedef __attribute__((ext_vector_type(8))) __bf16 bf16x8;
typedef __attribute__((ext_vector_type(8), aligned(8))) __bf16 bf16x8u;
typedef __attribute__((ext_vector_type(4), aligned(8))) __bf16 bf16x4a;
typedef __attribute__((ext_vector_type(4))) __bf16 bf16x4;
typedef __attribute__((ext_vector_type(4))) float f32x4;

union frag_u { struct { bf16x4a lo, hi; } p; bf16x8 v; };

// ---------------------------------------------------------------------------
// ws layout:
//   rtab    f32 [32][400]
//   costab  f32 [1024]  (pre-scaled by 223/224)
//   sintab  f32 [1024]  (pre-scaled by 223/224)
//   w2f     bf16 [20*3*6][64][8]  fragment-major w2, j ^ ((ka+icb)&1)*4
//   w1f     bf16 [12][64][8]      fragment-major w1 (grp = ks*6+ot), k>=60 -> 0
//   xp      bf16 [32][224][224][4] channels-last packed image
// ---------------------------------------------------------------------------

#define PACK_N   (NBATCH*IMGSZ*IMGSZ)
#define PACK_N4  (PACK_N/4)               // 401408, exact
#define PACK_B   ((PACK_N4 + 255)/256)    // 1568, exact
#define PREP_N   (ED*ED*20 + 12*64*8 + NBATCH*NR + NA + NBATCH)
#define PREP_B   ((PREP_N + 255)/256)

// merged image pack (4 px/thread, float4 loads) + tables + weight reorder
__global__ __launch_bounds__(256)
void prep_pack_kernel(const float* __restrict__ x,
                      const float* __restrict__ dist,
                      const float* __restrict__ w1,
                      const float* __restrict__ w2,
                      __bf16* __restrict__ xp,
                      float* __restrict__ rtab,
                      float* __restrict__ costab,
                      float* __restrict__ sintab,
                      __bf16* __restrict__ w2f,
                      __bf16* __restrict__ w1f,
                      float* __restrict__ theta_out) {
    const float PI = 3.14159265358979323846f;
    const float SC = 223.0f / 224.0f;
    int bid = blockIdx.x;

    if (bid < PACK_B) {                       // ---- image pack, 4 px/thread
        int i4 = bid*256 + threadIdx.x;
        if (i4 >= PACK_N4) return;
        int idx = i4 * 4;                     // pixel base; 50176 % 4 == 0 so
        int b  = idx / (IMGSZ*IMGSZ);         // all 4 px share one batch
        int px = idx - b*(IMGSZ*IMGSZ);
        const float* p = x + (size_t)b*3*IMGSZ*IMGSZ + px;
        f32x4 cr = *(const f32x4*)(p);
        f32x4 cg = *(const f32x4*)(p + IMGSZ*IMGSZ);
        f32x4 cb = *(const f32x4*)(p + 2*IMGSZ*IMGSZ);
        bf16x8 o0, o1;
        o0[0] = (__bf16)cr[0]; o0[1] = (__bf16)cg[0]; o0[2] = (__bf16)cb[0]; o0[3] = (__bf16)0.0f;
        o0[4] = (__bf16)cr[1]; o0[5] = (__bf16)cg[1]; o0[6] = (__bf16)cb[1]; o0[7] = (__bf16)0.0f;
        o1[0] = (__bf16)cr[2]; o1[1] = (__bf16)cg[2]; o1[2] = (__bf16)cb[2]; o1[3] = (__bf16)0.0f;
        o1[4] = (__bf16)cr[3]; o1[5] = (__bf16)cg[3]; o1[6] = (__bf16)cb[3]; o1[7] = (__bf16)0.0f;
        *(bf16x8*)(xp + (size_t)idx*4)     = o0;   // 16B, 32B-aligned
        *(bf16x8*)(xp + (size_t)idx*4 + 8) = o1;
        return;
    }

    int idx = (bid - PACK_B)*256 + threadIdx.x;
    if (idx < ED*ED*20) {
        // w2f: [(p*3+icb)*6+nt][lane][j], ic = icb*32+(lane>>4)*8+(j^sw)
        int j    = idx & 7;
        int lane = (idx >> 3) & 63;
        int grp  = idx >> 9;
        int nt   = grp % 6;
        int t    = grp / 6;
        int icb  = t % 3;
        int p    = t / 3;
        int sw   = (((p & 3) + icb) & 1) * 4;
        int oc = nt*16 + (lane & 15);
        int ic = icb*32 + (lane >> 4)*8 + (j ^ sw);
        w2f[idx] = (__bf16)w2[((size_t)(oc*ED + ic)*5 + (p >> 2))*4 + (p & 3)];
    } else if (idx < ED*ED*20 + 12*64*8) {
        // w1f: [grp=ks*6+ot][lane][j], A-frag value w1[oc][k]
        int i2   = idx - ED*ED*20;
        int j    = i2 & 7;
        int lane = (i2 >> 3) & 63;
        int grp  = i2 >> 9;
        int ks = grp / 6, ot = grp % 6;
        int oc = ot*16 + (lane & 15);
        int k  = ks*32 + (lane >> 4)*8 + j;
        w1f[i2] = (k < 60) ? (__bf16)w1[oc*60 + k] : (__bf16)0.0f;
    } else if (idx < ED*ED*20 + 12*64*8 + NBATCH*NR) {
        int i2 = idx - ED*ED*20 - 12*64*8;
        int b = i2 / NR, i = i2 % NR;
        float c0 = 0.2f + dist[b*4+0];
        float c1 = 0.2f + dist[b*4+1];
        float c2 = 0.2f + dist[b*4+2];
        float c3 = 0.2f + dist[b*4+3];
        float tmax = 0.5f * PI;
        float t  = tmax * ((float)i + 0.5f) / (float)NR;
        float t2 = t * t;
        float pt = t * (c0 + t2*(c1 + t2*(c2 + t2*c3)));
        float tm2 = tmax * tmax;
        float pm = tmax * (c0 + tm2*(c1 + tm2*(c2 + tm2*c3)));
        rtab[i2] = pt / pm * (0.5f * (float)IMGSZ);
    } else if (idx < ED*ED*20 + 12*64*8 + NBATCH*NR + NA) {
        int j = idx - ED*ED*20 - 12*64*8 - NBATCH*NR;
        float phi = 2.0f * PI * ((float)j + 0.5f) / (float)NA;
        costab[j] = cosf(phi) * SC;
        sintab[j] = sinf(phi) * SC;
    } else if (idx < PREP_N) {
        theta_out[idx - (ED*ED*20 + 12*64*8 + NBATCH*NR + NA)] = 0.5f * PI;
    }
}

// ---------------------------------------------------------------------------
// Mega kernel: polar bilinear sample (block-private region) -> conv1 (MFMA,
// D[oc][pixel]) -> t1f (conflict-free layout) -> conv2 (MFMA, wave =
// ka-quarter, register-accumulated over kr) -> reduce -> out.
// Block = (b, aq az-quarter, r2-pair): grid 1024, each block runs TWO r2
// units sequentially.  Why: LDS 32768 B -> 5 blocks/CU capacity; at grid
// 2048 that was rounds of 5+3 (ragged tail).  1024 blocks = 4/CU, one
// uniform round, AND each block's 368 KB w2f read is amortized over 2 units
// (737 -> 368 MB total L2 traffic).  w1f staged in LDS (NOT global: the
// compiler hoists loop-invariant global w1 loads into ~96 VGPRs and spills
// — round-1 regression, FETCH 9->430 MB).  __launch_bounds__(256,4): cap
// 128 VGPR, actual ~60, no spill.
// Loop body order: conv1 | bar | conv2 | sched_barrier | sample(kr+1) —
// so conv2's vmcnt waits never drain the sample gathers (in-order FIFO).
// ---------------------------------------------------------------------------
__global__ __launch_bounds__(256, 4)
void mega_kernel(const __bf16* __restrict__ xp,
                 const __bf16* __restrict__ w1f_g,
                 const __bf16* __restrict__ w2f,
                 const float* __restrict__ b1,
                 const float* __restrict__ b2,
                 const float* __restrict__ rtab,
                 const float* __restrict__ costab,
                 const float* __restrict__ sintab,
                 float* __restrict__ out) {
    __shared__ __attribute__((aligned(16))) char smem[32576];
    __bf16* s_samp = (__bf16*)smem;             // [15][266] elems 0..3989
    __bf16* t1f    = (__bf16*)(smem + 8000);    // [12 kk][4 quad][16 m][8]
    __bf16* s_w1f  = (__bf16*)(smem + 20288);   // [12 grp][64 lane][8]
    float*  red    = (float*)smem;              // [3][16][98] fp32 (aliases)

    int tid = threadIdx.x;
    int bid = blockIdx.x;                       // 1024
    int r2h = bid & 7;
    int aq  = (bid >> 3) & 3;
    int b   = bid >> 5;
    int wave = tid >> 6, lane = tid & 63, l15 = lane & 15, quad = lane >> 4;

    // stage w1 fragments into LDS (12288 B, coalesced); visible at barrier A
    #pragma unroll
    for (int i = 0; i < 3; ++i)
        *(bf16x8*)(s_w1f + i*2048 + tid*8) = *(const bf16x8*)(w1f_g + i*2048 + tid*8);

    // per-thread sampling constants: one azimuth column
    int az = aq*256 + tid;
    float sn = sintab[az];
    float cs = costab[az];
    const __bf16* xpb = xp + (size_t)b*IMGSZ*IMGSZ*4;
    const float* rb;

    // sample 5 radius rows (kr) x 3 ch into s_samp; stride-1 bf16 stores (free)
    auto sample = [&](int kr) {
        #pragma unroll
        for (int q = 0; q < 5; ++q) {
            float r  = rb[kr*5 + q];                       // wave-uniform
            float gx = fmaf(r, sn, 111.5f);
            float gy = fmaf(r, cs, 111.5f);
            float x0f = floorf(gx), y0f = floorf(gy);
            float wx1 = gx - x0f, wx0 = 1.0f - wx1;
            float wy1 = gy - y0f, wy0 = 1.0f - wy1;
            int ix = (int)x0f, iy = (int)y0f;
            ix = min(max(ix, 0), IMGSZ-2);                 // always in-bounds
            iy = min(max(iy, 0), IMGSZ-2);
            const __bf16* img = xpb + ((size_t)iy*IMGSZ + ix)*4;
            bf16x8u p0 = *(const bf16x8u*)img;
            bf16x8u p1 = *(const bf16x8u*)(img + IMGSZ*4);
            float w00 = wy0*wx0, w01 = wy0*wx1, w10 = wy1*wx0, w11 = wy1*wx1;
            #pragma unroll
            for (int c = 0; c < 3; ++c) {
                float v = w00*(float)p0[c] + w01*(float)p0[4+c]
                        + w10*(float)p1[c] + w11*(float)p1[4+c];
                s_samp[(c*5 + q)*SROW + tid] = (__bf16)v;
            }
        }
    };

    #pragma unroll 1
    for (int u = 0; u < 2; ++u) {
        int r2 = r2h*2 + u;
        rb = rtab + b*NR + r2*25;

        // u=1: prior unit's store phase reads red (aliases s_samp) — WAR sync
        if (u) __syncthreads();

        f32x4 acc2[6];
        #pragma unroll
        for (int nt = 0; nt < 6; ++nt) acc2[nt] = (f32x4){0.f,0.f,0.f,0.f};

        sample(0);

        for (int kr = 0; kr < 5; ++kr) {
            __syncthreads();   // A: samples(kr) + w1f visible; prev t1f reads done

            // ---- conv1: wave = pixel-tile, pixel = wave*16 + l15 in [0,64)
            int colb = (wave*16 + l15)*4;
            f32x4 acc1[6];
            #pragma unroll
            for (int ot = 0; ot < 6; ++ot) acc1[ot] = (f32x4){0.f,0.f,0.f,0.f};

            frag_u fa, fb;
            fa.p.lo = *(const bf16x4a*)&s_samp[(quad*2    )*SROW + colb];
            fa.p.hi = *(const bf16x4a*)&s_samp[(quad*2 + 1)*SROW + colb];
            fb.p.lo = *(const bf16x4a*)&s_samp[(8 + quad*2)*SROW + colb];
            if (quad == 3) fb.p.hi = (bf16x4a){};
            else           fb.p.hi = *(const bf16x4a*)&s_samp[(9 + quad*2)*SROW + colb];

            #pragma unroll
            for (int ot = 0; ot < 6; ++ot) {
                bf16x8 wf0 = *(const bf16x8*)(s_w1f + (ot     )*512 + lane*8);
                bf16x8 wf1 = *(const bf16x8*)(s_w1f + (6 + ot )*512 + lane*8);
                acc1[ot] = __builtin_amdgcn_mfma_f32_16x16x32_bf16(wf0, fa.v, acc1[ot], 0, 0, 0);
                acc1[ot] = __builtin_amdgcn_mfma_f32_16x16x32_bf16(wf1, fb.v, acc1[ot], 0, 0, 0);
            }

            // epilogue: col=l15 (pixel), row=quad*4+r (oc=ic); scatter to t1f
            int pixel = wave*16 + l15;
            int a2l = pixel >> 2, ka = pixel & 3;
            #pragma unroll
            for (int ot = 0; ot < 6; ++ot) {
                f32x4 v = acc1[ot] + *(const f32x4*)(b1 + ot*16 + quad*4);
                bf16x4a wv;
                wv[0] = (__bf16)v[0]; wv[1] = (__bf16)v[1];
                wv[2] = (__bf16)v[2]; wv[3] = (__bf16)v[3];
                int icbase = ot*16 + quad*4;
                int kk = ka*3 + (icbase >> 5);
                int qT = (icbase >> 3) & 3;
                int jb = (icbase & 7) ^ ((kk & 1)*4);
                *(bf16x4a*)&t1f[((kk*4 + qT)*16 + a2l)*8 + jb] = wv;
            }
            __syncthreads();   // B: t1f ready; s_samp reads done

            // ---- conv2 FIRST: wave's ka = wave; 3 k-steps (vm loads self-owned)
            #pragma unroll
            for (int icb = 0; icb < 3; ++icb) {
                int kk = wave*3 + icb;
                int p  = kr*4 + wave;
                bf16x8 af = *(const bf16x8*)&t1f[(kk*64 + lane)*8];   // lane-contig
                const __bf16* wp = w2f + (size_t)((p*3 + icb)*6)*512 + lane*8;
                #pragma unroll
                for (int nt = 0; nt < 6; ++nt) {
                    bf16x8 bf = *(const bf16x8*)(wp + nt*512);
                    acc2[nt] = __builtin_amdgcn_mfma_f32_16x16x32_bf16(af, bf, acc2[nt], 0, 0, 0);
                }
            }

            // keep sample's gathers AFTER conv2's loads (vmcnt FIFO ordering)
            __builtin_amdgcn_sched_barrier(0);

            if (kr < 4) sample(kr + 1);   // gather latency hidden by other waves
        }

        // ---- ka-quarter reduction (red aliases s_samp+t1f; w1f untouched)
        __syncthreads();
        if (wave) {
            float* rw = red + (wave - 1)*1568;     // 16*98
            #pragma unroll
            for (int nt = 0; nt < 6; ++nt)
                #pragma unroll
                for (int r = 0; r < 4; ++r)
                    rw[(quad*4 + r)*98 + nt*16 + l15] = acc2[nt][r];
        }
        __syncthreads();
        if (wave == 0) {
            size_t ob = ((size_t)b*1024 + r2*64 + aq*16)*ED;
            #pragma unroll
            for (int nt = 0; nt < 6; ++nt) {
                int oc = nt*16 + l15;
                float bias = b2[oc];
                #pragma unroll
                for (int r = 0; r < 4; ++r) {
                    int row = quad*4 + r;
                    float v = acc2[nt][r] + bias
                            + red[row*98 + oc]
                            + red[1568 + row*98 + oc]
                            + red[3136 + row*98 + oc];
                    out[ob + (size_t)row*ED + oc] = v;
                }
            }
        }
    }
}

extern "C" void kernel_launch(void* const* d_in, const int* in_sizes, int n_in,
                              void* d_out, int out_size, void* d_ws, size_t ws_size,
                              hipStream_t stream) {
    const float* x    = (const float*)d_in[0];
    const float* dist = (const float*)d_in[1];
    const float* w1   = (const float*)d_in[2];
    const float* b1   = (const float*)d_in[3];
    const float* w2   = (const float*)d_in[4];
    const float* b2   = (const float*)d_in[5];
    float* out = (float*)d_out;

    float* rtab   = (float*)d_ws;                 // 12800
    float* costab = rtab + NBATCH*NR;             // 1024
    float* sintab = costab + NA;                  // 1024
    __bf16* w2f   = (__bf16*)(sintab + NA);       // 184320 bf16
    __bf16* w1f   = w2f + ED*ED*20;               // 6144 bf16
    __bf16* xp    = w1f + 12*64*8;                // 32*224*224*4 bf16

    float* theta_out = out + (size_t)NBATCH*1024*ED;

    prep_pack_kernel<<<PACK_B + PREP_B, 256, 0, stream>>>(
        x, dist, w1, w2, xp, rtab, costab, sintab, w2f, w1f, theta_out);
    mega_kernel<<<NBATCH*32, 256, 0, stream>>>(
        xp, w1f, w2f, b1, b2, rtab, costab, sintab, out);
}

// Round 5
// 145.770 us; speedup vs baseline: 1.8155x; 1.1322x over previous
//
#include <hip/hip_runtime.h>
#include <hip/hip_bf16.h>
#include <math.h>

#define NBATCH 32
#define IMGSZ  224
#define NR     400
#define NA     1024
#define ED     96
#define SROW   266   // s_samp row stride in elems (256 cols + 10; odd dword)

typedef __attribute__((ext_vector_type(8))) __bf16 bf16x8;
typedef __attribute__((ext_vector_type(8), aligned(8))) __bf16 bf16x8u;
typedef __attribute__((ext_vector_type(4), aligned(8))) __bf16 bf16x4a;
typedef __attribute__((ext_vector_type(4))) __bf16 bf16x4;
typedef __attribute__((ext_vector_type(4))) float f32x4;

union frag_u { struct { bf16x4a lo, hi; } p; bf16x8 v; };

// ---------------------------------------------------------------------------
// ws layout:
//   rtab    f32 [32][400]
//   costab  f32 [1024]  (pre-scaled by 223/224)
//   sintab  f32 [1024]  (pre-scaled by 223/224)
//   w2f     bf16 [20*3*6][64][8]  fragment-major w2, j ^ ((ka+icb)&1)*4
//   w1f     bf16 [12][64][8]      fragment-major w1 (grp = ks*6+ot), k>=60 -> 0
//   xp      RD=1: bf16 [32][224][224][8] ROW-DUPLICATED channels-last image:
//           entry (b,y,x) = {c0,c1,c2,0 @ row y | c0,c1,c2,0 @ row y+1}.
//           A bilinear sample = two ADJACENT 16B loads (cols x0,x0+1) ->
//           ~1.25 cache lines/point vs 2.25 when the two row loads sit
//           1792B apart. Mega is gather-latency bound (57% issue-idle).
//           Costs 2x image footprint: ws total 26.14 MB.
//           RD=0: bf16 [32][224][224][4] (round-0 layout, ws total 13.3 MB).
//   HOST picks RD from ws_size; RD=0 path is bit-identical to the proven
//   round-0 binary. Rounds 3-4 "container failed twice" carried no timing
//   block => acquisition failure, kernel never ran; audit found no OOB or
//   alignment fault in either path. Resubmitting the same experiment.
// ---------------------------------------------------------------------------

#define PACK_N   (NBATCH*IMGSZ*IMGSZ)
#define PACK_N4  (PACK_N/4)               // 401408, exact
#define PACK_B   ((PACK_N4 + 255)/256)    // 1568, exact
#define PREP_N   (ED*ED*20 + 12*64*8 + NBATCH*NR + NA + NBATCH)
#define PREP_B   ((PREP_N + 255)/256)

// merged image pack (4 px/thread, float4 loads) + tables + weight reorder
template<bool RD>
__global__ __launch_bounds__(256)
void prep_pack_kernel(const float* __restrict__ x,
                      const float* __restrict__ dist,
                      const float* __restrict__ w1,
                      const float* __restrict__ w2,
                      __bf16* __restrict__ xp,
                      float* __restrict__ rtab,
                      float* __restrict__ costab,
                      float* __restrict__ sintab,
                      __bf16* __restrict__ w2f,
                      __bf16* __restrict__ w1f,
                      float* __restrict__ theta_out) {
    const float PI = 3.14159265358979323846f;
    const float SC = 223.0f / 224.0f;
    int bid = blockIdx.x;

    if (bid < PACK_B) {                       // ---- image pack, 4 px/thread
        int i4 = bid*256 + threadIdx.x;
        if (i4 >= PACK_N4) return;
        int idx = i4 * 4;                     // pixel base; row-aligned since
        int b   = idx / (IMGSZ*IMGSZ);        // 50176%4==0 and 224%4==0
        int rem = idx - b*(IMGSZ*IMGSZ);
        const float* pl = x + (size_t)b*3*IMGSZ*IMGSZ;
        if constexpr (RD) {
            int y    = rem / IMGSZ;
            int xcol = rem - y*IMGSZ;
            int yn = min(y + 1, IMGSZ - 1);   // y=223 entries unused (iy<=222)
            f32x4 r0[3], r1[3];
            #pragma unroll
            for (int c = 0; c < 3; ++c) {
                r0[c] = *(const f32x4*)(pl + (size_t)c*IMGSZ*IMGSZ + y *IMGSZ + xcol);
                r1[c] = *(const f32x4*)(pl + (size_t)c*IMGSZ*IMGSZ + yn*IMGSZ + xcol);
            }
            #pragma unroll
            for (int e = 0; e < 4; ++e) {
                bf16x8 o;
                o[0] = (__bf16)r0[0][e]; o[1] = (__bf16)r0[1][e];
                o[2] = (__bf16)r0[2][e]; o[3] = (__bf16)0.0f;
                o[4] = (__bf16)r1[0][e]; o[5] = (__bf16)r1[1][e];
                o[6] = (__bf16)r1[2][e]; o[7] = (__bf16)0.0f;
                *(bf16x8*)(xp + (size_t)(idx + e)*8) = o;   // 16B coalesced
            }
        } else {
            const float* p = pl + rem;
            f32x4 cr = *(const f32x4*)(p);
            f32x4 cg = *(const f32x4*)(p + IMGSZ*IMGSZ);
            f32x4 cb = *(const f32x4*)(p + 2*IMGSZ*IMGSZ);
            bf16x8 o0, o1;
            o0[0] = (__bf16)cr[0]; o0[1] = (__bf16)cg[0]; o0[2] = (__bf16)cb[0]; o0[3] = (__bf16)0.0f;
            o0[4] = (__bf16)cr[1]; o0[5] = (__bf16)cg[1]; o0[6] = (__bf16)cb[1]; o0[7] = (__bf16)0.0f;
            o1[0] = (__bf16)cr[2]; o1[1] = (__bf16)cg[2]; o1[2] = (__bf16)cb[2]; o1[3] = (__bf16)0.0f;
            o1[4] = (__bf16)cr[3]; o1[5] = (__bf16)cg[3]; o1[6] = (__bf16)cb[3]; o1[7] = (__bf16)0.0f;
            *(bf16x8*)(xp + (size_t)idx*4)     = o0;
            *(bf16x8*)(xp + (size_t)idx*4 + 8) = o1;
        }
        return;
    }

    int idx = (bid - PACK_B)*256 + threadIdx.x;
    if (idx < ED*ED*20) {
        // w2f: [(p*3+icb)*6+nt][lane][j], ic = icb*32+(lane>>4)*8+(j^sw)
        int j    = idx & 7;
        int lane = (idx >> 3) & 63;
        int grp  = idx >> 9;
        int nt   = grp % 6;
        int t    = grp / 6;
        int icb  = t % 3;
        int p    = t / 3;
        int sw   = (((p & 3) + icb) & 1) * 4;
        int oc = nt*16 + (lane & 15);
        int ic = icb*32 + (lane >> 4)*8 + (j ^ sw);
        w2f[idx] = (__bf16)w2[((size_t)(oc*ED + ic)*5 + (p >> 2))*4 + (p & 3)];
    } else if (idx < ED*ED*20 + 12*64*8) {
        // w1f: [grp=ks*6+ot][lane][j], A-frag value w1[oc][k]
        int i2   = idx - ED*ED*20;
        int j    = i2 & 7;
        int lane = (i2 >> 3) & 63;
        int grp  = i2 >> 9;
        int ks = grp / 6, ot = grp % 6;
        int oc = ot*16 + (lane & 15);
        int k  = ks*32 + (lane >> 4)*8 + j;
        w1f[i2] = (k < 60) ? (__bf16)w1[oc*60 + k] : (__bf16)0.0f;
    } else if (idx < ED*ED*20 + 12*64*8 + NBATCH*NR) {
        int i2 = idx - ED*ED*20 - 12*64*8;
        int b = i2 / NR, i = i2 % NR;
        float c0 = 0.2f + dist[b*4+0];
        float c1 = 0.2f + dist[b*4+1];
        float c2 = 0.2f + dist[b*4+2];
        float c3 = 0.2f + dist[b*4+3];
        float tmax = 0.5f * PI;
        float t  = tmax * ((float)i + 0.5f) / (float)NR;
        float t2 = t * t;
        float pt = t * (c0 + t2*(c1 + t2*(c2 + t2*c3)));
        float tm2 = tmax * tmax;
        float pm = tmax * (c0 + tm2*(c1 + tm2*(c2 + tm2*c3)));
        rtab[i2] = pt / pm * (0.5f * (float)IMGSZ);
    } else if (idx < ED*ED*20 + 12*64*8 + NBATCH*NR + NA) {
        int j = idx - ED*ED*20 - 12*64*8 - NBATCH*NR;
        float phi = 2.0f * PI * ((float)j + 0.5f) / (float)NA;
        costab[j] = cosf(phi) * SC;
        sintab[j] = sinf(phi) * SC;
    } else if (idx < PREP_N) {
        theta_out[idx - (ED*ED*20 + 12*64*8 + NBATCH*NR + NA)] = 0.5f * PI;
    }
}

// ---------------------------------------------------------------------------
// Mega kernel: polar bilinear sample (block-private region) -> conv1 (MFMA,
// D[oc][pixel]) -> t1f (conflict-free layout) -> conv2 (MFMA, wave =
// ka-quarter, register-accumulated over kr) -> reduce -> out.
// Block = (b, aq az-quarter, r2). Grid 2048, 256 thr = 4 waves, LDS 31.8 KB
// -> 5 blocks/CU (20 waves). Round-2 lesson: dropping to 4 blocks/CU (grid
// 1024, 2 units/block) cost 37%/unit — latency-bound, occupancy is first-
// order; keep grid 2048. w1f stays in LDS (global w1 hoists ~96 VGPR and
// spills — round-1 regression, FETCH 9->430 MB).
// Loop body order: conv1 | bar | conv2 | sched_barrier | sample(kr+1) —
// so conv2's vmcnt waits never drain the sample gathers (in-order FIFO).
// ---------------------------------------------------------------------------
template<bool RD>
__global__ __launch_bounds__(256, 4)
void mega_kernel(const __bf16* __restrict__ xp,
                 const __bf16* __restrict__ w1f_g,
                 const __bf16* __restrict__ w2f,
                 const float* __restrict__ b1,
                 const float* __restrict__ b2,
                 const float* __restrict__ rtab,
                 const float* __restrict__ costab,
                 const float* __restrict__ sintab,
                 float* __restrict__ out) {
    __shared__ __attribute__((aligned(16))) char smem[32576];
    __bf16* s_samp = (__bf16*)smem;             // [15][266] elems 0..3989
    __bf16* t1f    = (__bf16*)(smem + 8000);    // [12 kk][4 quad][16 m][8]
    __bf16* s_w1f  = (__bf16*)(smem + 20288);   // [12 grp][64 lane][8]
    float*  red    = (float*)smem;              // [3][16][98] fp32 (aliases)

    int tid = threadIdx.x;
    int bid = blockIdx.x;                       // 2048
    int r2 = bid & 15;
    int aq = (bid >> 4) & 3;
    int b  = bid >> 6;
    int wave = tid >> 6, lane = tid & 63, l15 = lane & 15, quad = lane >> 4;

    // stage w1 fragments into LDS (12288 B, coalesced)
    #pragma unroll
    for (int i = 0; i < 3; ++i)
        *(bf16x8*)(s_w1f + i*2048 + tid*8) = *(const bf16x8*)(w1f_g + i*2048 + tid*8);

    // per-thread sampling constants: one azimuth column
    int az = aq*256 + tid;
    float sn = sintab[az];
    float cs = costab[az];
    const __bf16* xpb = xp + (size_t)b*IMGSZ*IMGSZ*(RD ? 8 : 4);
    const float* rb = rtab + b*NR + r2*25;

    f32x4 acc2[6];
    #pragma unroll
    for (int nt = 0; nt < 6; ++nt) acc2[nt] = (f32x4){0.f,0.f,0.f,0.f};

    // sample 5 radius rows (kr) x 3 ch into s_samp; stride-1 bf16 stores (free)
    auto sample = [&](int kr) {
        #pragma unroll
        for (int q = 0; q < 5; ++q) {
            float r  = rb[kr*5 + q];                       // wave-uniform
            float gx = fmaf(r, sn, 111.5f);
            float gy = fmaf(r, cs, 111.5f);
            float x0f = floorf(gx), y0f = floorf(gy);
            float wx1 = gx - x0f, wx0 = 1.0f - wx1;
            float wy1 = gy - y0f, wy0 = 1.0f - wy1;
            int ix = (int)x0f, iy = (int)y0f;
            ix = min(max(ix, 0), IMGSZ-2);                 // always in-bounds
            iy = min(max(iy, 0), IMGSZ-2);
            float w00 = wy0*wx0, w01 = wy0*wx1, w10 = wy1*wx0, w11 = wy1*wx1;
            if constexpr (RD) {
                // row-dup: entry (y,x) = 16B {rows y,y+1}; two ADJACENT loads
                const __bf16* img = xpb + ((size_t)iy*IMGSZ + ix)*8;
                bf16x8u p0 = *(const bf16x8u*)img;        // col x0: rows y|y+1
                bf16x8u p1 = *(const bf16x8u*)(img + 8);  // col x1: rows y|y+1
                #pragma unroll
                for (int c = 0; c < 3; ++c) {
                    float v = w00*(float)p0[c]   + w01*(float)p1[c]
                            + w10*(float)p0[4+c] + w11*(float)p1[4+c];
                    s_samp[(c*5 + q)*SROW + tid] = (__bf16)v;
                }
            } else {
                // round-0: entry (y,x) = 8B {c0,c1,c2,0}; rows 1792B apart
                const __bf16* img = xpb + ((size_t)iy*IMGSZ + ix)*4;
                bf16x8u p0 = *(const bf16x8u*)img;              // row y: x0,x1
                bf16x8u p1 = *(const bf16x8u*)(img + IMGSZ*4);  // row y+1
                #pragma unroll
                for (int c = 0; c < 3; ++c) {
                    float v = w00*(float)p0[c] + w01*(float)p0[4+c]
                            + w10*(float)p1[c] + w11*(float)p1[4+c];
                    s_samp[(c*5 + q)*SROW + tid] = (__bf16)v;
                }
            }
        }
    };

    sample(0);

    for (int kr = 0; kr < 5; ++kr) {
        __syncthreads();   // A: samples(kr) visible; prev conv2 t1f reads done

        // ---- conv1: wave = pixel-tile, pixel = wave*16 + l15 in [0,64)
        int colb = (wave*16 + l15)*4;
        f32x4 acc1[6];
        #pragma unroll
        for (int ot = 0; ot < 6; ++ot) acc1[ot] = (f32x4){0.f,0.f,0.f,0.f};

        frag_u fa, fb;
        fa.p.lo = *(const bf16x4a*)&s_samp[(quad*2    )*SROW + colb];
        fa.p.hi = *(const bf16x4a*)&s_samp[(quad*2 + 1)*SROW + colb];
        fb.p.lo = *(const bf16x4a*)&s_samp[(8 + quad*2)*SROW + colb];
        if (quad == 3) fb.p.hi = (bf16x4a){};
        else           fb.p.hi = *(const bf16x4a*)&s_samp[(9 + quad*2)*SROW + colb];

        #pragma unroll
        for (int ot = 0; ot < 6; ++ot) {
            bf16x8 wf0 = *(const bf16x8*)(s_w1f + (ot     )*512 + lane*8);
            bf16x8 wf1 = *(const bf16x8*)(s_w1f + (6 + ot )*512 + lane*8);
            acc1[ot] = __builtin_amdgcn_mfma_f32_16x16x32_bf16(wf0, fa.v, acc1[ot], 0, 0, 0);
            acc1[ot] = __builtin_amdgcn_mfma_f32_16x16x32_bf16(wf1, fb.v, acc1[ot], 0, 0, 0);
        }

        // epilogue: col=l15 (pixel), row=quad*4+r (oc=ic); scatter to t1f
        int pixel = wave*16 + l15;
        int a2l = pixel >> 2, ka = pixel & 3;
        #pragma unroll
        for (int ot = 0; ot < 6; ++ot) {
            f32x4 v = acc1[ot] + *(const f32x4*)(b1 + ot*16 + quad*4);
            bf16x4a wv;
            wv[0] = (__bf16)v[0]; wv[1] = (__bf16)v[1];
            wv[2] = (__bf16)v[2]; wv[3] = (__bf16)v[3];
            int icbase = ot*16 + quad*4;
            int kk = ka*3 + (icbase >> 5);
            int qT = (icbase >> 3) & 3;
            int jb = (icbase & 7) ^ ((kk & 1)*4);
            *(bf16x4a*)&t1f[((kk*4 + qT)*16 + a2l)*8 + jb] = wv;
        }
        __syncthreads();   // B: t1f ready; s_samp reads done

        // ---- conv2 FIRST: wave's ka = wave; 3 k-steps (vm loads self-owned)
        #pragma unroll
        for (int icb = 0; icb < 3; ++icb) {
            int kk = wave*3 + icb;
            int p  = kr*4 + wave;
            bf16x8 af = *(const bf16x8*)&t1f[(kk*64 + lane)*8];   // lane-contig
            const __bf16* wp = w2f + (size_t)((p*3 + icb)*6)*512 + lane*8;
            #pragma unroll
            for (int nt = 0; nt < 6; ++nt) {
                bf16x8 bf = *(const bf16x8*)(wp + nt*512);
                acc2[nt] = __builtin_amdgcn_mfma_f32_16x16x32_bf16(af, bf, acc2[nt], 0, 0, 0);
            }
        }

        // keep sample's gathers AFTER conv2's loads (vmcnt FIFO ordering)
        __builtin_amdgcn_sched_barrier(0);

        if (kr < 4) sample(kr + 1);   // gather latency hidden by other waves
    }

    // ---- ka-quarter reduction (red aliases s_samp+t1f; w1f region untouched)
    __syncthreads();
    if (wave) {
        float* rw = red + (wave - 1)*1568;     // 16*98
        #pragma unroll
        for (int nt = 0; nt < 6; ++nt)
            #pragma unroll
            for (int r = 0; r < 4; ++r)
                rw[(quad*4 + r)*98 + nt*16 + l15] = acc2[nt][r];
    }
    __syncthreads();
    if (wave == 0) {
        size_t ob = ((size_t)b*1024 + r2*64 + aq*16)*ED;
        #pragma unroll
        for (int nt = 0; nt < 6; ++nt) {
            int oc = nt*16 + l15;
            float bias = b2[oc];
            #pragma unroll
            for (int r = 0; r < 4; ++r) {
                int row = quad*4 + r;
                float v = acc2[nt][r] + bias
                        + red[row*98 + oc]
                        + red[1568 + row*98 + oc]
                        + red[3136 + row*98 + oc];
                out[ob + (size_t)row*ED + oc] = v;
            }
        }
    }
}

extern "C" void kernel_launch(void* const* d_in, const int* in_sizes, int n_in,
                              void* d_out, int out_size, void* d_ws, size_t ws_size,
                              hipStream_t stream) {
    const float* x    = (const float*)d_in[0];
    const float* dist = (const float*)d_in[1];
    const float* w1   = (const float*)d_in[2];
    const float* b1   = (const float*)d_in[3];
    const float* w2   = (const float*)d_in[4];
    const float* b2   = (const float*)d_in[5];
    float* out = (float*)d_out;

    float* rtab   = (float*)d_ws;                 // 12800 f32
    float* costab = rtab + NBATCH*NR;             // 1024 f32
    float* sintab = costab + NA;                  // 1024 f32
    __bf16* w2f   = (__bf16*)(sintab + NA);       // 184320 bf16
    __bf16* w1f   = w2f + ED*ED*20;               // 6144 bf16
    __bf16* xp    = w1f + 12*64*8;                // RD: 25.7MB, else 12.8MB

    float* theta_out = out + (size_t)NBATCH*1024*ED;

    // fixed prefix = 440,320 B; RD xp needs 25,690,112 B => 26.14 MB total
    bool rd = ws_size >= (size_t)27000000;

    if (rd) {
        prep_pack_kernel<true><<<PACK_B + PREP_B, 256, 0, stream>>>(
            x, dist, w1, w2, xp, rtab, costab, sintab, w2f, w1f, theta_out);
        mega_kernel<true><<<NBATCH*16*4, 256, 0, stream>>>(
            xp, w1f, w2f, b1, b2, rtab, costab, sintab, out);
    } else {
        prep_pack_kernel<false><<<PACK_B + PREP_B, 256, 0, stream>>>(
            x, dist, w1, w2, xp, rtab, costab, sintab, w2f, w1f, theta_out);
        mega_kernel<false><<<NBATCH*16*4, 256, 0, stream>>>(
            xp, w1f, w2f, b1, b2, rtab, costab, sintab, out);
    }
}